// Round 1
// baseline (384.987 us; speedup 1.0000x reference)
//
#include <hip/hip_runtime.h>
#include <hip/hip_bf16.h>

// R1: replace global-atomic histogram (k_hist, 77us, atomic-rate-bound at ~26G/s)
// with LDS-bucketed u4 partial histograms (k_histp) + nibble merge in k_abfrc.

#define NN    1195
#define NUSER 805
#define NITEM 390
#define DD    64
#define BB    2048
#define NPAD  1216          // 19*64, padded node/k count
#define E_TOT 1000000
#define E_SUB 500000
#define MT    19            // m-tiles per graph
#define KT    8             // K-split factor
#define CHUNK 3             // ceil(19/8) k-subtiles per block
#define LSTR  72            // LDS row stride in bf16 elems
#define OUT2STRIDE (NN*DD)
#define CPG    299          // comb blocks per graph = ceil(1195*64/256)
#define P8W    152          // u32 words per histogram row (1216 u4 cells)

typedef unsigned int uint;
typedef unsigned short u16;
typedef unsigned char u8;
typedef __attribute__((ext_vector_type(8))) short short8;
typedef __attribute__((ext_vector_type(4))) float f32x4;

__device__ __forceinline__ float wsum(float v) {
#pragma unroll
    for (int m = 32; m > 0; m >>= 1) v += __shfl_xor(v, m, 64);
    return v;
}
__device__ __forceinline__ u16 f2b(float f) {           // fp32 -> bf16 RNE bits
    uint u = __float_as_uint(f);
    return (u16)((u + 0x7FFFu + ((u >> 16) & 1u)) >> 16);
}
__device__ __forceinline__ float b2f16(u16 b) { return __uint_as_float(((uint)b) << 16); }

// ---- converted-input layout (floats, relative to OFF_CVT) ----
#define CVT_EMB   0
#define CVT_W1    76480
#define CVT_B1    80576
#define CVT_W2    80640
#define CVT_B2    84736
#define CVT_MLPW  84800
#define CVT_MLPB  88896
#define CVT_GAMMA 88960
#define CVT_BETA  89024
#define CVT_TOTAL 89088

// ---------------- workspace layout (floats) ----------------
// Persistent prefix (alive across the histogram phase), then an aliasable POOL.
// P8 (u4 partial histograms) lives at OFF_POOL: it is written by k_histp and
// fully consumed by k_abfrc BEFORE any pool member (PART/H1/H2/OUT2/CU/CI/H)
// is written, so aliasing is safe. S=4 fits inside the pool; S=8 extends
// 2.6 MB past it (gated on ws_size).
constexpr size_t alignUp64(size_t x) { return (x + 63) & ~size_t(63); }
constexpr size_t OFF_BNS  = 0;                                        // [128]
constexpr size_t OFF_CNSS = 128;                                      // [256]
constexpr size_t MEMSET_FLOATS = 384;                                 // zeroed region
constexpr size_t OFF_FLAG = 384;                                      // [16]
constexpr size_t OFF_CVT  = 448;                                      // [CVT_TOTAL]
constexpr size_t OFF_ABF  = alignUp64(OFF_CVT + CVT_TOTAL);           // bf16 A 3*NN*NPAD u16
constexpr size_t OFF_RC   = alignUp64(OFF_ABF + (3ull * NN * NPAD) / 2);
constexpr size_t OFF_POOL = alignUp64(OFF_RC + 3ull * NPAD);
constexpr size_t OFF_PART = OFF_POOL;                                 // fp32 partials KT*3*NPAD*64
constexpr size_t OFF_H1   = alignUp64(OFF_PART + (size_t)KT * 3 * NPAD * 64);
constexpr size_t OFF_H2   = alignUp64(OFF_H1 + 64ull * NPAD);
constexpr size_t OFF_OUT2 = alignUp64(OFF_H2 + 3ull * 64 * NPAD);
constexpr size_t OFF_CU   = alignUp64(OFF_OUT2 + 3ull * NN * DD);     // [448*64]
constexpr size_t OFF_CI   = alignUp64(OFF_CU + 448ull * DD);
constexpr size_t OFF_H    = alignUp64(OFF_CI + (size_t)NUSER * DD);
constexpr size_t POOL_END = alignUp64(OFF_H + (size_t)BB * DD);

// ---------------- kernels ----------------

// convert small float inputs to fp32, detect dtype, accumulate view-0 user col-sumsq
__global__ __launch_bounds__(256) void k_cvt_all(const void* presc,
        const void* p1, const void* p2, const void* p3, const void* p4,
        const void* p5, const void* p6, const void* p7, const void* p8, const void* p9,
        float* __restrict__ dst, float* __restrict__ cnss, int* __restrict__ flag) {
    int isbf = (((const u16*)presc)[0] == 0x3F80u) ? 1 : 0;   // presc[0][0]==1.0 always
    int t = threadIdx.x;
    int i = blockIdx.x * 256 + t;
    if (i == 0) *flag = isbf;
    const void* src; int off;
    if      (i < CVT_W1)    { src = p1; off = i; }
    else if (i < CVT_B1)    { src = p2; off = i - CVT_W1; }
    else if (i < CVT_B2)    { src = p3; off = i - CVT_B1; }
    else if (i < CVT_MLPW)  { src = p4; off = i - CVT_W2; }
    else if (i < CVT_MLPB)  { src = p5; off = i - CVT_B2; }
    else if (i < CVT_GAMMA) { src = p6; off = i - CVT_MLPW; }
    else if (i < CVT_BETA)  { src = p7; off = i - CVT_MLPB; }
    else                    { src = p8; off = i - CVT_GAMMA; }
    // NOTE: mapping above shifted — fix with explicit chain (kept explicit below)
    (void)p9; (void)src; (void)off;
    const void* s2; int o2;
    if      (i < CVT_W1)    { s2 = p1; o2 = i; }
    else if (i < CVT_B1)    { s2 = p2; o2 = i - CVT_W1; }
    else if (i < CVT_W2)    { s2 = p3; o2 = i - CVT_B1; }
    else if (i < CVT_B2)    { s2 = p4; o2 = i - CVT_W2; }
    else if (i < CVT_MLPW)  { s2 = p5; o2 = i - CVT_B2; }
    else if (i < CVT_MLPB)  { s2 = p6; o2 = i - CVT_MLPW; }
    else if (i < CVT_GAMMA) { s2 = p7; o2 = i - CVT_MLPB; }
    else if (i < CVT_BETA)  { s2 = p8; o2 = i - CVT_GAMMA; }
    else                    { s2 = p9; o2 = i - CVT_BETA; }
    float v = isbf ? __bfloat162float(((const __hip_bfloat16*)s2)[o2])
                   : ((const float*)s2)[o2];
    dst[i] = v;
    // view-0 column sumsq over user rows of emb (emb occupies i < 76480, 64 dims/row)
    float x2 = (i < NUSER * 64) ? v * v : 0.0f;
    __shared__ float sd[256];
    sd[t] = x2;
    __syncthreads();
    if (t < 64 && blockIdx.x * 256 < NUSER * 64) {
        float s = sd[t] + sd[t + 64] + sd[t + 128] + sd[t + 192];
        if (s != 0.0f) atomicAdd(&cnss[t], s);
    }
}

// LDS-bucketed u4 partial histograms.
// block = (g, row-range r of `rows`, edge-slice p of S). LDS holds rows x 1216
// u4 counts (rows*152 u32). Writes its range to partial copy p (plain stores).
__global__ __launch_bounds__(1024) void k_histp(const int* __restrict__ tg,
        const int* __restrict__ s1, const int* __restrict__ s2,
        uint* __restrict__ P8, int R, int rows, int S) {
    extern __shared__ uint lds[];
    int b = blockIdx.x;
    int p = b % S;
    int rg = b / S;
    int r = rg % R;
    int g = rg / R;
    int r0 = r * rows;
    int t = threadIdx.x;

    int nw = rows * P8W;
    for (int i = t; i < nw; i += 1024) lds[i] = 0u;
    __syncthreads();

    const int* eg = (g == 0) ? tg : (g == 1 ? s1 : s2);
    int Eg = (g == 0) ? E_TOT : E_SUB;
    int per = Eg / S;                      // exact for S in {4,8}
    int e0 = p * per, e1 = e0 + per;
    const int* srcp = eg;
    const int* dstp = eg + Eg;
    for (int i = e0 + t; i < e1; i += 1024) {
        int row = dstp[i] - r0;
        if ((unsigned)row < (unsigned)rows) {
            int s = srcp[i];
            atomicAdd(&lds[row * P8W + (s >> 3)], 1u << ((s & 7) * 4));
        }
    }
    __syncthreads();

    int rmax = rows; if (r0 + rmax > NN) rmax = NN - r0;
    uint* out = P8 + ((size_t)p * 3 + g) * NN * P8W + (size_t)r0 * P8W;
    int n = rmax * P8W;
    for (int i = t; i < n; i += 1024) out[i] = lds[i];   // contiguous, coalesced
}

// merge S u4 partial copies -> bf16 A row (pad cols zero) + reciprocal in-degree
__global__ __launch_bounds__(256) void k_abfrc(const uint* __restrict__ P8, int S,
        u16* __restrict__ Abf, float* __restrict__ rcnt) {
    int row = blockIdx.x;            // 0..3*NN-1
    int g = row / NN, m = row % NN;
    int t = threadIdx.x, w = t >> 6;
    float partial = 0.0f;
    if (t < P8W) {
        uint cnt[8] = {0, 0, 0, 0, 0, 0, 0, 0};
        for (int p = 0; p < S; ++p) {
            uint v = P8[(((size_t)p * 3 + g) * NN + m) * P8W + t];
#pragma unroll
            for (int k = 0; k < 8; ++k) cnt[k] += (v >> (4 * k)) & 15u;
        }
        uint4 o;
        o.x = (uint)f2b((float)cnt[0]) | ((uint)f2b((float)cnt[1]) << 16);
        o.y = (uint)f2b((float)cnt[2]) | ((uint)f2b((float)cnt[3]) << 16);
        o.z = (uint)f2b((float)cnt[4]) | ((uint)f2b((float)cnt[5]) << 16);
        o.w = (uint)f2b((float)cnt[6]) | ((uint)f2b((float)cnt[7]) << 16);
        *(uint4*)(Abf + (size_t)row * NPAD + t * 8) = o;
#pragma unroll
        for (int k = 0; k < 8; ++k) partial += (float)cnt[k];
    }
    partial = wsum(partial);
    __shared__ float ws4[4];
    if ((t & 63) == 0) ws4[w] = partial;
    __syncthreads();
    if (t == 0)
        rcnt[g * NPAD + m] = 1.0f / fmaxf(ws4[0] + ws4[1] + ws4[2] + ws4[3], 1.0f);
}

// Linear transform -> transposed bf16 hi/lo planes [g][64 dims][NPAD nodes].
// fromPart=1: input rows = tanh(sum_kt part * rcnt) (fuses layer-1 combine).
__global__ __launch_bounds__(256) void k_xf(const float* __restrict__ x, size_t xgstride,
        const float* __restrict__ part, const float* __restrict__ rcnt, int fromPart,
        const float* __restrict__ W, const float* __restrict__ bias,
        u16* __restrict__ Hhi, u16* __restrict__ Hlo, size_t hgstride) {
    int b = blockIdx.x;
    int g = b / MT, nt = b % MT;
    int t = threadIdx.x, w = t >> 6, l = t & 63;
    int n0 = nt * 64;
    __shared__ float Ws[64 * 65];
    __shared__ float bs[64];
    __shared__ float Ts[64 * 68];
    for (int i = t; i < 4096; i += 256) Ws[(i >> 6) * 65 + (i & 63)] = W[i];
    if (t < 64) bs[t] = bias[t];
    float xr[16];
#pragma unroll
    for (int i = 0; i < 16; ++i) {
        int node = n0 + w * 16 + i;
        float v = 0.0f;
        if (node < NN) {
            if (fromPart) {
                float s = 0.0f;
#pragma unroll
                for (int k = 0; k < KT; ++k)
                    s += part[(((size_t)k * 3 + g) * NPAD + node) * 64 + l];
                v = tanhf(s * rcnt[g * NPAD + node]);
            } else {
                v = x[xgstride * g + (size_t)node * 64 + l];
            }
        }
        xr[i] = v;
    }
    __syncthreads();
#pragma unroll
    for (int i = 0; i < 16; ++i) {
        int node = n0 + w * 16 + i;
        float acc = 0.0f;
        if (node < NN) {
            acc = bs[l];
#pragma unroll
            for (int k = 0; k < 64; ++k)
                acc = fmaf(__shfl(xr[i], k, 64), Ws[l * 65 + k], acc);
        }
        Ts[l * 68 + w * 16 + i] = acc;
    }
    __syncthreads();
    int d = t >> 2, seg = t & 3;
    u16 hb[16], lb[16];
#pragma unroll
    for (int j = 0; j < 16; ++j) {
        float v = Ts[d * 68 + seg * 16 + j];
        u16 h = f2b(v);
        hb[j] = h;
        lb[j] = f2b(v - b2f16(h));
    }
    size_t base = hgstride * g + (size_t)d * NPAD + n0 + seg * 16;
#pragma unroll
    for (int j = 0; j < 4; ++j) {
        uint2 ph, pl;
        ph.x = (uint)hb[j*4]   | ((uint)hb[j*4+1] << 16);
        ph.y = (uint)hb[j*4+2] | ((uint)hb[j*4+3] << 16);
        pl.x = (uint)lb[j*4]   | ((uint)lb[j*4+1] << 16);
        pl.y = (uint)lb[j*4+2] | ((uint)lb[j*4+3] << 16);
        *(uint2*)(Hhi + base + j*4) = ph;
        *(uint2*)(Hlo + base + j*4) = pl;
    }
}

// MFMA aggregation with split-bf16 B; K-split partials
__global__ __launch_bounds__(256) void k_aggp(const u16* __restrict__ Abf,
        const u16* __restrict__ Hhi, const u16* __restrict__ Hlo, size_t hstride,
        float* __restrict__ part) {
    int b = blockIdx.x;
    int kt = b & 7;
    int mt = (b >> 3) % MT;
    int g  = (b >> 3) / MT;
    int t = threadIdx.x, w = t >> 6, l = t & 63;
    __shared__ u16 As[64 * LSTR], Bh[64 * LSTR], Bl[64 * LSTR];
    f32x4 acc[4];
#pragma unroll
    for (int p = 0; p < 4; ++p) acc[p] = (f32x4){0.f, 0.f, 0.f, 0.f};
    int m0 = mt * 64;
    const u16* Ag = Abf + (size_t)g * NN * NPAD;
    const u16* Hg = Hhi + hstride * g;
    const u16* Lg = Hlo + hstride * g;
    int st0 = kt * CHUNK;
    int st1 = st0 + CHUNK; if (st1 > MT) st1 = MT;
    int rr = t >> 4, c4 = (t & 15) * 4;
    for (int st = st0; st < st1; ++st) {
        int s0 = st * 64;
        __syncthreads();
#pragma unroll
        for (int pass = 0; pass < 4; ++pass) {
            int r = pass * 16 + rr;
            uint2 av = {0u, 0u};
            if (m0 + r < NN) av = *(const uint2*)(Ag + (size_t)(m0 + r) * NPAD + s0 + c4);
            *(uint2*)(As + r * LSTR + c4) = av;
            *(uint2*)(Bh + r * LSTR + c4) = *(const uint2*)(Hg + (size_t)r * NPAD + s0 + c4);
            *(uint2*)(Bl + r * LSTR + c4) = *(const uint2*)(Lg + (size_t)r * NPAD + s0 + c4);
        }
        __syncthreads();
        int mrow = w * 16 + (l & 15);
        int q8 = (l >> 4) * 8;
#pragma unroll
        for (int ks = 0; ks < 2; ++ks) {
            short8 a = *(const short8*)(As + mrow * LSTR + ks * 32 + q8);
#pragma unroll
            for (int p = 0; p < 4; ++p) {
                int nrow = p * 16 + (l & 15);
                short8 bh = *(const short8*)(Bh + nrow * LSTR + ks * 32 + q8);
                short8 bl = *(const short8*)(Bl + nrow * LSTR + ks * 32 + q8);
                acc[p] = __builtin_amdgcn_mfma_f32_16x16x32_bf16(a, bh, acc[p], 0, 0, 0);
                acc[p] = __builtin_amdgcn_mfma_f32_16x16x32_bf16(a, bl, acc[p], 0, 0, 0);
            }
        }
    }
    int q = l >> 4;
#pragma unroll
    for (int p = 0; p < 4; ++p) {
        int n = p * 16 + (l & 15);
#pragma unroll
        for (int r = 0; r < 4; ++r) {
            int m = m0 + w * 16 + q * 4 + r;
            if (m < NN)
                part[(((size_t)kt * 3 + g) * NPAD + m) * 64 + n] = acc[p][r];
        }
    }
}

// layer-2 combine + views-1..3 user column sumsq accumulation
__global__ __launch_bounds__(256) void k_comb(const float* __restrict__ part,
        const float* __restrict__ rcnt, float* __restrict__ out, float* __restrict__ cnss) {
    int g = blockIdx.x / CPG, bi = blockIdx.x % CPG;
    int t = threadIdx.x;
    int idx = bi * 256 + t;                 // within graph
    int m = idx >> 6, n = idx & 63;
    bool valid = idx < NN * 64;
    float v = 0.0f;
    if (valid) {
        float s = 0.0f;
#pragma unroll
        for (int k = 0; k < KT; ++k)
            s += part[(((size_t)k * 3 + g) * NPAD + m) * 64 + n];
        v = tanhf(s * rcnt[g * NPAD + m]);
        out[(size_t)g * NN * 64 + idx] = v;
    }
    float x2 = (valid && m < NUSER) ? v * v : 0.0f;
    __shared__ float sd[256];
    sd[t] = x2;
    __syncthreads();
    if (t < 64) {
        float s = sd[t] + sd[t + 64] + sd[t + 128] + sd[t + 192];
        if (s != 0.0f) atomicAdd(&cnss[(g + 1) * 64 + t], s);
    }
}

// cu (item rows, 4-view row-norm fusion) + ci (user rows, 4-view col-norm fusion)
__global__ void k_cuci(const float* __restrict__ embf, const float* __restrict__ out2,
                       const float* __restrict__ cnss, float* __restrict__ cu,
                       float* __restrict__ ci) {
    int b = blockIdx.x, l = threadIdx.x;
    if (b < 448) {
        if (b >= NITEM) { cu[(size_t)b * DD + l] = 0.0f; return; }
        int node = NUSER + b;
        const float* v0 = embf + (size_t)node * DD;
        const float* v1 = out2 + (size_t)node * DD;
        const float* v2 = out2 + OUT2STRIDE + (size_t)node * DD;
        const float* v3 = out2 + 2ull * OUT2STRIDE + (size_t)node * DD;
        float total = 0.0f;
        { float x = v0[l]; float ss = wsum(x * x); total += x / sqrtf(ss); }
        { float x = v1[l]; float ss = wsum(x * x); total += x / sqrtf(ss); }
        { float x = v2[l]; float ss = wsum(x * x); total += x / sqrtf(ss); }
        { float x = v3[l]; float ss = wsum(x * x); total += x / sqrtf(ss); }
        cu[(size_t)b * DD + l] = 0.25f * total;
    } else {
        int u = b - 448;
        size_t i = (size_t)u * DD + l;
        float s = embf[i] / sqrtf(cnss[l])
                + out2[i] / sqrtf(cnss[64 + l])
                + out2[OUT2STRIDE + i] / sqrtf(cnss[128 + l])
                + out2[2ull * OUT2STRIDE + i] / sqrtf(cnss[192 + l]);
        ci[i] = 0.25f * s;
    }
}

// e_synd = (presc @ c_u)/rowsum; h_pre = e_synd @ mlpW^T + b; + BN partial sums
__global__ __launch_bounds__(256) void k_esynd(const void* __restrict__ presc,
        const float* __restrict__ cu, const float* __restrict__ mlpW,
        const float* __restrict__ mlpB, const int* __restrict__ flag,
        float* __restrict__ hpre, float* __restrict__ bnsum) {
    int t = threadIdx.x, w = t >> 6, l = t & 63;
    int b0 = blockIdx.x * 16 + w * 4;
    int isbf = *flag;
    const __hip_bfloat16* pB = (const __hip_bfloat16*)presc;
    const float* pF = (const float*)presc;
    float acc[4] = {0, 0, 0, 0}, ps[4] = {0, 0, 0, 0};
    for (int j0 = 0; j0 < NITEM; j0 += 64) {
        int j = j0 + l;
        float pv[4];
#pragma unroll
        for (int r = 0; r < 4; ++r) {
            float v = 0.0f;
            if (j < NITEM) {
                size_t idx = (size_t)(b0 + r) * NITEM + j;
                v = isbf ? __bfloat162float(pB[idx]) : pF[idx];
            }
            pv[r] = v; ps[r] += v;
        }
#pragma unroll 16
        for (int jj = 0; jj < 64; ++jj) {
            float cv = cu[(size_t)(j0 + jj) * DD + l];
#pragma unroll
            for (int r = 0; r < 4; ++r)
                acc[r] = fmaf(__shfl(pv[r], jj, 64), cv, acc[r]);
        }
    }
    float e[4];
#pragma unroll
    for (int r = 0; r < 4; ++r) e[r] = acc[r] / wsum(ps[r]);
    float bb = mlpB[l];
    float h[4] = {bb, bb, bb, bb};
    for (int k = 0; k < 64; ++k) {
        float wv = mlpW[l * 64 + k];
#pragma unroll
        for (int r = 0; r < 4; ++r)
            h[r] = fmaf(__shfl(e[r], k, 64), wv, h[r]);
    }
    float s1 = 0.0f, s2 = 0.0f;
#pragma unroll
    for (int r = 0; r < 4; ++r) {
        hpre[(size_t)(b0 + r) * DD + l] = h[r];
        s1 += h[r]; s2 = fmaf(h[r], h[r], s2);
    }
    __shared__ float l1[4][64], l2[4][64];
    l1[w][l] = s1; l2[w][l] = s2;
    __syncthreads();
    if (w == 0) {
        float a = l1[0][l] + l1[1][l] + l1[2][l] + l1[3][l];
        float c = l2[0][l] + l2[1][l] + l2[2][l] + l2[3][l];
        atomicAdd(&bnsum[l], a);
        atomicAdd(&bnsum[64 + l], c);
    }
}

// pre[b][u] = relu(BN(h_pre[b])) . c_i[u]; BN finalized from bnsum
__global__ __launch_bounds__(256) void k_final(const float* __restrict__ hpre,
        const float* __restrict__ bnsum, const float* __restrict__ gamma,
        const float* __restrict__ beta, const float* __restrict__ ci,
        void* __restrict__ out, const int* __restrict__ flag) {
    int b0 = blockIdx.x * 8;
    int t = threadIdx.x;
    int isbf = *flag;
    __shared__ float mn[64], rs[64];
    __shared__ float hs[8][64];
    __shared__ float cs[64 * 65];
    if (t < 64) {
        float mean = bnsum[t] * (1.0f / BB);
        float var = bnsum[64 + t] * (1.0f / BB) - mean * mean;
        mn[t] = mean;
        rs[t] = 1.0f / sqrtf(var + 1e-5f);
    }
    __syncthreads();
    for (int i = t; i < 8 * 64; i += 256) {
        int r = i / 64, d = i % 64;
        float v = hpre[(size_t)(b0 + r) * DD + d];
        v = (v - mn[d]) * rs[d] * gamma[d] + beta[d];
        hs[r][d] = fmaxf(v, 0.0f);
    }
    int cc = t % 64;
    int rsx = t / 64;
    for (int ct = 0; ct < 13; ++ct) {
        __syncthreads();
        for (int i = t; i < 64 * 64; i += 256) {
            int c = i / 64, d = i % 64;
            int col = ct * 64 + c;
            cs[c * 65 + d] = (col < NUSER) ? ci[(size_t)col * DD + d] : 0.0f;
        }
        __syncthreads();
        float a0 = 0.0f, a1 = 0.0f;
#pragma unroll
        for (int d = 0; d < 64; ++d) {
            float cv = cs[cc * 65 + d];
            a0 = fmaf(hs[rsx][d], cv, a0);
            a1 = fmaf(hs[rsx + 4][d], cv, a1);
        }
        int col = ct * 64 + cc;
        if (col < NUSER) {
            size_t o0 = (size_t)(b0 + rsx) * NUSER + col;
            size_t o1 = (size_t)(b0 + rsx + 4) * NUSER + col;
            if (isbf) {
                ((__hip_bfloat16*)out)[o0] = __float2bfloat16(a0);
                ((__hip_bfloat16*)out)[o1] = __float2bfloat16(a1);
            } else {
                ((float*)out)[o0] = a0;
                ((float*)out)[o1] = a1;
            }
        }
    }
}

extern "C" void kernel_launch(void* const* d_in, const int* in_sizes, int n_in,
                              void* d_out, int out_size, void* d_ws, size_t ws_size,
                              hipStream_t stream) {
    const void* presc = d_in[1];
    const void* emb   = d_in[2];
    const void* W1    = d_in[3];
    const void* b1    = d_in[4];
    const void* W2    = d_in[5];
    const void* b2    = d_in[6];
    const void* mlpW  = d_in[7];
    const void* mlpB  = d_in[8];
    const void* gamma = d_in[9];
    const void* beta  = d_in[10];
    const int* tg = (const int*)d_in[11];
    const int* s1 = (const int*)d_in[12];
    const int* s2 = (const int*)d_in[13];
    float* ws = (float*)d_ws;
    (void)in_sizes; (void)n_in; (void)out_size;

    float* bnsum = ws + OFF_BNS;
    float* cnss  = ws + OFF_CNSS;
    int*   flag  = (int*)(ws + OFF_FLAG);
    float* cvt   = ws + OFF_CVT;
    float* embF  = cvt + CVT_EMB;
    float* W1F   = cvt + CVT_W1;
    float* b1F   = cvt + CVT_B1;
    float* W2F   = cvt + CVT_W2;
    float* b2F   = cvt + CVT_B2;
    float* mlpWF = cvt + CVT_MLPW;
    float* mlpBF = cvt + CVT_MLPB;
    float* gamF  = cvt + CVT_GAMMA;
    float* betF  = cvt + CVT_BETA;
    u16*   Abf   = (u16*)(ws + OFF_ABF);
    float* rcnt  = ws + OFF_RC;
    uint*  P8    = (uint*)(ws + OFF_POOL);
    float* part  = ws + OFF_PART;
    u16*   H1hi  = (u16*)(ws + OFF_H1);
    u16*   H1lo  = H1hi + 64ull * NPAD;
    u16*   H2hi  = (u16*)(ws + OFF_H2);
    u16*   H2lo  = H2hi + 3ull * 64 * NPAD;
    float* out2  = ws + OFF_OUT2;
    float* cu    = ws + OFF_CU;
    float* ci    = ws + OFF_CI;
    float* hpre  = ws + OFF_H;

    // one-time: opt into 152 KB dynamic LDS for k_histp (256 rows/block);
    // fall back to 96 rows (58 KB, under default limit) if refused.
    static int g_rows = 0;
    if (g_rows == 0) {
        hipError_t e = hipFuncSetAttribute((const void*)k_histp,
                hipFuncAttributeMaxDynamicSharedMemorySize, 256 * P8W * 4);
        g_rows = (e == hipSuccess) ? 256 : 96;
    }
    int rows = g_rows;
    int R = (NN + rows - 1) / rows;
    size_t need8 = (OFF_POOL + 8ull * 3 * NN * P8W) * sizeof(float);
    int S = (ws_size >= need8) ? 8 : 4;     // S=4 path aliases entirely inside pool

    hipMemsetAsync(ws, 0, MEMSET_FLOATS * sizeof(float), stream);   // bnsum + cnss
    k_cvt_all<<<CVT_TOTAL / 256, 256, 0, stream>>>(
        presc, emb, W1, b1, W2, b2, mlpW, mlpB, gamma, beta, cvt, cnss, flag);

    k_histp<<<3 * R * S, 1024, rows * P8W * 4, stream>>>(tg, s1, s2, P8, R, rows, S);
    k_abfrc<<<3 * NN, 256, 0, stream>>>(P8, S, Abf, rcnt);

    // layer 1
    k_xf<<<MT, 256, 0, stream>>>(embF, 0, nullptr, nullptr, 0, W1F, b1F, H1hi, H1lo, 0);
    k_aggp<<<3 * MT * KT, 256, 0, stream>>>(Abf, H1hi, H1lo, 0, part);
    // layer 2
    k_xf<<<3 * MT, 256, 0, stream>>>(nullptr, 0, part, rcnt, 1, W2F, b2F, H2hi, H2lo, 64ull * NPAD);
    k_aggp<<<3 * MT * KT, 256, 0, stream>>>(Abf, H2hi, H2lo, 64ull * NPAD, part);
    k_comb<<<3 * CPG, 256, 0, stream>>>(part, rcnt, out2, cnss);

    // view fusion
    k_cuci<<<448 + NUSER, 64, 0, stream>>>(embF, out2, cnss, cu, ci);

    // pooling + MLP(+BN partials) + final
    k_esynd<<<BB / 16, 256, 0, stream>>>(presc, cu, mlpWF, mlpBF, flag, hpre, bnsum);
    k_final<<<BB / 8, 256, 0, stream>>>(hpre, bnsum, gamF, betF, ci, d_out, flag);
}

// Round 2
// 342.065 us; speedup vs baseline: 1.1255x; 1.1255x over previous
//
#include <hip/hip_runtime.h>
#include <hip/hip_bf16.h>

// R2: k_histp reshaped for latency hiding. R1 failed (105-117us vs 77us baseline)
// because grid=120 blocks / 152KB LDS -> <half the CUs, 1 block/CU, scalar
// control-dependent loads (VALUBusy 3%, Occupancy 12%). Now: rows=96 (57KB static
// LDS, 2 blocks/CU), 512 thr (16 waves/CU), S=16 slices (grid 624), int4
// vectorized unconditional edge loads, uint4 write-out.

#define NN    1195
#define NUSER 805
#define NITEM 390
#define DD    64
#define BB    2048
#define NPAD  1216          // 19*64, padded node/k count
#define E_TOT 1000000
#define E_SUB 500000
#define MT    19            // m-tiles per graph
#define KT    8             // K-split factor
#define CHUNK 3             // ceil(19/8) k-subtiles per block
#define LSTR  72            // LDS row stride in bf16 elems
#define OUT2STRIDE (NN*DD)
#define CPG    299          // comb blocks per graph = ceil(1195*64/256)
#define P8W    152          // u32 words per histogram row (1216 u4 cells)
#define ROWS   96           // histogram rows per block (57KB LDS)
#define RB     13           // ceil(NN/ROWS)

typedef unsigned int uint;
typedef unsigned short u16;
typedef unsigned char u8;
typedef __attribute__((ext_vector_type(8))) short short8;
typedef __attribute__((ext_vector_type(4))) float f32x4;

__device__ __forceinline__ float wsum(float v) {
#pragma unroll
    for (int m = 32; m > 0; m >>= 1) v += __shfl_xor(v, m, 64);
    return v;
}
__device__ __forceinline__ u16 f2b(float f) {           // fp32 -> bf16 RNE bits
    uint u = __float_as_uint(f);
    return (u16)((u + 0x7FFFu + ((u >> 16) & 1u)) >> 16);
}
__device__ __forceinline__ float b2f16(u16 b) { return __uint_as_float(((uint)b) << 16); }

// ---- converted-input layout (floats, relative to OFF_CVT) ----
#define CVT_EMB   0
#define CVT_W1    76480
#define CVT_B1    80576
#define CVT_W2    80640
#define CVT_B2    84736
#define CVT_MLPW  84800
#define CVT_MLPB  88896
#define CVT_GAMMA 88960
#define CVT_BETA  89024
#define CVT_TOTAL 89088

// ---------------- workspace layout (floats) ----------------
// Persistent prefix, then aliasable POOL. P8 (u4 partial histograms) lives at
// OFF_POOL: written by k_histp, fully consumed by k_abfrc BEFORE any pool
// member (PART/H1/H2/OUT2/CU/CI/H) is written, so aliasing is safe.
// S=4 fits inside the pool; S=8/16 extend past it (gated on ws_size).
constexpr size_t alignUp64(size_t x) { return (x + 63) & ~size_t(63); }
constexpr size_t OFF_BNS  = 0;                                        // [128]
constexpr size_t OFF_CNSS = 128;                                      // [256]
constexpr size_t MEMSET_FLOATS = 384;                                 // zeroed region
constexpr size_t OFF_FLAG = 384;                                      // [16]
constexpr size_t OFF_CVT  = 448;                                      // [CVT_TOTAL]
constexpr size_t OFF_ABF  = alignUp64(OFF_CVT + CVT_TOTAL);           // bf16 A 3*NN*NPAD u16
constexpr size_t OFF_RC   = alignUp64(OFF_ABF + (3ull * NN * NPAD) / 2);
constexpr size_t OFF_POOL = alignUp64(OFF_RC + 3ull * NPAD);
constexpr size_t OFF_PART = OFF_POOL;                                 // fp32 partials KT*3*NPAD*64
constexpr size_t OFF_H1   = alignUp64(OFF_PART + (size_t)KT * 3 * NPAD * 64);
constexpr size_t OFF_H2   = alignUp64(OFF_H1 + 64ull * NPAD);
constexpr size_t OFF_OUT2 = alignUp64(OFF_H2 + 3ull * 64 * NPAD);
constexpr size_t OFF_CU   = alignUp64(OFF_OUT2 + 3ull * NN * DD);     // [448*64]
constexpr size_t OFF_CI   = alignUp64(OFF_CU + 448ull * DD);
constexpr size_t OFF_H    = alignUp64(OFF_CI + (size_t)NUSER * DD);
constexpr size_t POOL_END = alignUp64(OFF_H + (size_t)BB * DD);

// ---------------- kernels ----------------

// convert small float inputs to fp32, detect dtype, accumulate view-0 user col-sumsq
__global__ __launch_bounds__(256) void k_cvt_all(const void* presc,
        const void* p1, const void* p2, const void* p3, const void* p4,
        const void* p5, const void* p6, const void* p7, const void* p8, const void* p9,
        float* __restrict__ dst, float* __restrict__ cnss, int* __restrict__ flag) {
    int isbf = (((const u16*)presc)[0] == 0x3F80u) ? 1 : 0;   // presc[0][0]==1.0 always
    int t = threadIdx.x;
    int i = blockIdx.x * 256 + t;
    if (i == 0) *flag = isbf;
    const void* s2; int o2;
    if      (i < CVT_W1)    { s2 = p1; o2 = i; }
    else if (i < CVT_B1)    { s2 = p2; o2 = i - CVT_W1; }
    else if (i < CVT_W2)    { s2 = p3; o2 = i - CVT_B1; }
    else if (i < CVT_B2)    { s2 = p4; o2 = i - CVT_W2; }
    else if (i < CVT_MLPW)  { s2 = p5; o2 = i - CVT_B2; }
    else if (i < CVT_MLPB)  { s2 = p6; o2 = i - CVT_MLPW; }
    else if (i < CVT_GAMMA) { s2 = p7; o2 = i - CVT_MLPB; }
    else if (i < CVT_BETA)  { s2 = p8; o2 = i - CVT_GAMMA; }
    else                    { s2 = p9; o2 = i - CVT_BETA; }
    float v = isbf ? __bfloat162float(((const __hip_bfloat16*)s2)[o2])
                   : ((const float*)s2)[o2];
    dst[i] = v;
    // view-0 column sumsq over user rows of emb (emb occupies i < 76480, 64 dims/row)
    float x2 = (i < NUSER * 64) ? v * v : 0.0f;
    __shared__ float sd[256];
    sd[t] = x2;
    __syncthreads();
    if (t < 64 && blockIdx.x * 256 < NUSER * 64) {
        float s = sd[t] + sd[t + 64] + sd[t + 128] + sd[t + 192];
        if (s != 0.0f) atomicAdd(&cnss[t], s);
    }
}

// LDS-bucketed u4 partial histograms.
// block = (g, row-range r of ROWS, edge-slice p of S). LDS = ROWS x 1216 u4.
// Same-slice blocks co-locate on one XCD (S multiple of 8 -> b%8 == p%8) so the
// slice stays in that XCD's L2 across the R-fold re-scan.
__global__ __launch_bounds__(512) void k_histp(const int* __restrict__ tg,
        const int* __restrict__ s1, const int* __restrict__ s2,
        uint* __restrict__ P8, int S) {
    __shared__ __align__(16) uint lds[ROWS * P8W];
    int b = blockIdx.x;
    int p = b % S;
    int rg = b / S;
    int r = rg % RB;
    int g = rg / RB;
    int r0 = r * ROWS;
    int t = threadIdx.x;

    {
        uint4* l4 = (uint4*)lds;
        for (int i = t; i < (ROWS * P8W) >> 2; i += 512) l4[i] = (uint4){0u, 0u, 0u, 0u};
    }
    __syncthreads();

    const int* eg = (g == 0) ? tg : (g == 1 ? s1 : s2);
    int Eg = (g == 0) ? E_TOT : E_SUB;
    // 4-aligned slice bounds: every int4 load is 16B-aligned, no tail.
    int e0 = (int)(((long)p * Eg / S) & ~3L);
    int e1 = (p == S - 1) ? Eg : (int)(((long)(p + 1) * Eg / S) & ~3L);
    const int* srcp = eg;
    const int* dstp = eg + Eg;
    for (int i = e0 + t * 4; i < e1; i += 512 * 4) {
        int4 d4 = *(const int4*)(dstp + i);
        int4 s4 = *(const int4*)(srcp + i);
        int rw;
        rw = d4.x - r0; if ((unsigned)rw < ROWS) atomicAdd(&lds[rw * P8W + (s4.x >> 3)], 1u << ((s4.x & 7) * 4));
        rw = d4.y - r0; if ((unsigned)rw < ROWS) atomicAdd(&lds[rw * P8W + (s4.y >> 3)], 1u << ((s4.y & 7) * 4));
        rw = d4.z - r0; if ((unsigned)rw < ROWS) atomicAdd(&lds[rw * P8W + (s4.z >> 3)], 1u << ((s4.z & 7) * 4));
        rw = d4.w - r0; if ((unsigned)rw < ROWS) atomicAdd(&lds[rw * P8W + (s4.w >> 3)], 1u << ((s4.w & 7) * 4));
    }
    __syncthreads();

    int rmax = ROWS; if (r0 + rmax > NN) rmax = NN - r0;
    uint* out = P8 + ((size_t)p * 3 + g) * NN * P8W + (size_t)r0 * P8W;  // word-off %4==0 -> 16B aligned
    int n4 = (rmax * P8W) >> 2;
    const uint4* l4 = (const uint4*)lds;
    uint4* o4 = (uint4*)out;
    for (int i = t; i < n4; i += 512) o4[i] = l4[i];   // contiguous, coalesced
}

// merge S u4 partial copies -> bf16 A row (pad cols zero) + reciprocal in-degree
__global__ __launch_bounds__(256) void k_abfrc(const uint* __restrict__ P8, int S,
        u16* __restrict__ Abf, float* __restrict__ rcnt) {
    int row = blockIdx.x;            // 0..3*NN-1
    int g = row / NN, m = row % NN;
    int t = threadIdx.x, w = t >> 6;
    float partial = 0.0f;
    if (t < P8W) {
        uint cnt[8] = {0, 0, 0, 0, 0, 0, 0, 0};
        for (int p = 0; p < S; ++p) {
            uint v = P8[(((size_t)p * 3 + g) * NN + m) * P8W + t];
#pragma unroll
            for (int k = 0; k < 8; ++k) cnt[k] += (v >> (4 * k)) & 15u;
        }
        uint4 o;
        o.x = (uint)f2b((float)cnt[0]) | ((uint)f2b((float)cnt[1]) << 16);
        o.y = (uint)f2b((float)cnt[2]) | ((uint)f2b((float)cnt[3]) << 16);
        o.z = (uint)f2b((float)cnt[4]) | ((uint)f2b((float)cnt[5]) << 16);
        o.w = (uint)f2b((float)cnt[6]) | ((uint)f2b((float)cnt[7]) << 16);
        *(uint4*)(Abf + (size_t)row * NPAD + t * 8) = o;
#pragma unroll
        for (int k = 0; k < 8; ++k) partial += (float)cnt[k];
    }
    partial = wsum(partial);
    __shared__ float ws4[4];
    if ((t & 63) == 0) ws4[w] = partial;
    __syncthreads();
    if (t == 0)
        rcnt[g * NPAD + m] = 1.0f / fmaxf(ws4[0] + ws4[1] + ws4[2] + ws4[3], 1.0f);
}

// Linear transform -> transposed bf16 hi/lo planes [g][64 dims][NPAD nodes].
// fromPart=1: input rows = tanh(sum_kt part * rcnt) (fuses layer-1 combine).
__global__ __launch_bounds__(256) void k_xf(const float* __restrict__ x, size_t xgstride,
        const float* __restrict__ part, const float* __restrict__ rcnt, int fromPart,
        const float* __restrict__ W, const float* __restrict__ bias,
        u16* __restrict__ Hhi, u16* __restrict__ Hlo, size_t hgstride) {
    int b = blockIdx.x;
    int g = b / MT, nt = b % MT;
    int t = threadIdx.x, w = t >> 6, l = t & 63;
    int n0 = nt * 64;
    __shared__ float Ws[64 * 65];
    __shared__ float bs[64];
    __shared__ float Ts[64 * 68];
    for (int i = t; i < 4096; i += 256) Ws[(i >> 6) * 65 + (i & 63)] = W[i];
    if (t < 64) bs[t] = bias[t];
    float xr[16];
#pragma unroll
    for (int i = 0; i < 16; ++i) {
        int node = n0 + w * 16 + i;
        float v = 0.0f;
        if (node < NN) {
            if (fromPart) {
                float s = 0.0f;
#pragma unroll
                for (int k = 0; k < KT; ++k)
                    s += part[(((size_t)k * 3 + g) * NPAD + node) * 64 + l];
                v = tanhf(s * rcnt[g * NPAD + node]);
            } else {
                v = x[xgstride * g + (size_t)node * 64 + l];
            }
        }
        xr[i] = v;
    }
    __syncthreads();
#pragma unroll
    for (int i = 0; i < 16; ++i) {
        int node = n0 + w * 16 + i;
        float acc = 0.0f;
        if (node < NN) {
            acc = bs[l];
#pragma unroll
            for (int k = 0; k < 64; ++k)
                acc = fmaf(__shfl(xr[i], k, 64), Ws[l * 65 + k], acc);
        }
        Ts[l * 68 + w * 16 + i] = acc;
    }
    __syncthreads();
    int d = t >> 2, seg = t & 3;
    u16 hb[16], lb[16];
#pragma unroll
    for (int j = 0; j < 16; ++j) {
        float v = Ts[d * 68 + seg * 16 + j];
        u16 h = f2b(v);
        hb[j] = h;
        lb[j] = f2b(v - b2f16(h));
    }
    size_t base = hgstride * g + (size_t)d * NPAD + n0 + seg * 16;
#pragma unroll
    for (int j = 0; j < 4; ++j) {
        uint2 ph, pl;
        ph.x = (uint)hb[j*4]   | ((uint)hb[j*4+1] << 16);
        ph.y = (uint)hb[j*4+2] | ((uint)hb[j*4+3] << 16);
        pl.x = (uint)lb[j*4]   | ((uint)lb[j*4+1] << 16);
        pl.y = (uint)lb[j*4+2] | ((uint)lb[j*4+3] << 16);
        *(uint2*)(Hhi + base + j*4) = ph;
        *(uint2*)(Hlo + base + j*4) = pl;
    }
}

// MFMA aggregation with split-bf16 B; K-split partials
__global__ __launch_bounds__(256) void k_aggp(const u16* __restrict__ Abf,
        const u16* __restrict__ Hhi, const u16* __restrict__ Hlo, size_t hstride,
        float* __restrict__ part) {
    int b = blockIdx.x;
    int kt = b & 7;
    int mt = (b >> 3) % MT;
    int g  = (b >> 3) / MT;
    int t = threadIdx.x, w = t >> 6, l = t & 63;
    __shared__ u16 As[64 * LSTR], Bh[64 * LSTR], Bl[64 * LSTR];
    f32x4 acc[4];
#pragma unroll
    for (int p = 0; p < 4; ++p) acc[p] = (f32x4){0.f, 0.f, 0.f, 0.f};
    int m0 = mt * 64;
    const u16* Ag = Abf + (size_t)g * NN * NPAD;
    const u16* Hg = Hhi + hstride * g;
    const u16* Lg = Hlo + hstride * g;
    int st0 = kt * CHUNK;
    int st1 = st0 + CHUNK; if (st1 > MT) st1 = MT;
    int rr = t >> 4, c4 = (t & 15) * 4;
    for (int st = st0; st < st1; ++st) {
        int s0 = st * 64;
        __syncthreads();
#pragma unroll
        for (int pass = 0; pass < 4; ++pass) {
            int r = pass * 16 + rr;
            uint2 av = {0u, 0u};
            if (m0 + r < NN) av = *(const uint2*)(Ag + (size_t)(m0 + r) * NPAD + s0 + c4);
            *(uint2*)(As + r * LSTR + c4) = av;
            *(uint2*)(Bh + r * LSTR + c4) = *(const uint2*)(Hg + (size_t)r * NPAD + s0 + c4);
            *(uint2*)(Bl + r * LSTR + c4) = *(const uint2*)(Lg + (size_t)r * NPAD + s0 + c4);
        }
        __syncthreads();
        int mrow = w * 16 + (l & 15);
        int q8 = (l >> 4) * 8;
#pragma unroll
        for (int ks = 0; ks < 2; ++ks) {
            short8 a = *(const short8*)(As + mrow * LSTR + ks * 32 + q8);
#pragma unroll
            for (int p = 0; p < 4; ++p) {
                int nrow = p * 16 + (l & 15);
                short8 bh = *(const short8*)(Bh + nrow * LSTR + ks * 32 + q8);
                short8 bl = *(const short8*)(Bl + nrow * LSTR + ks * 32 + q8);
                acc[p] = __builtin_amdgcn_mfma_f32_16x16x32_bf16(a, bh, acc[p], 0, 0, 0);
                acc[p] = __builtin_amdgcn_mfma_f32_16x16x32_bf16(a, bl, acc[p], 0, 0, 0);
            }
        }
    }
    int q = l >> 4;
#pragma unroll
    for (int p = 0; p < 4; ++p) {
        int n = p * 16 + (l & 15);
#pragma unroll
        for (int r = 0; r < 4; ++r) {
            int m = m0 + w * 16 + q * 4 + r;
            if (m < NN)
                part[(((size_t)kt * 3 + g) * NPAD + m) * 64 + n] = acc[p][r];
        }
    }
}

// layer-2 combine + views-1..3 user column sumsq accumulation
__global__ __launch_bounds__(256) void k_comb(const float* __restrict__ part,
        const float* __restrict__ rcnt, float* __restrict__ out, float* __restrict__ cnss) {
    int g = blockIdx.x / CPG, bi = blockIdx.x % CPG;
    int t = threadIdx.x;
    int idx = bi * 256 + t;                 // within graph
    int m = idx >> 6, n = idx & 63;
    bool valid = idx < NN * 64;
    float v = 0.0f;
    if (valid) {
        float s = 0.0f;
#pragma unroll
        for (int k = 0; k < KT; ++k)
            s += part[(((size_t)k * 3 + g) * NPAD + m) * 64 + n];
        v = tanhf(s * rcnt[g * NPAD + m]);
        out[(size_t)g * NN * 64 + idx] = v;
    }
    float x2 = (valid && m < NUSER) ? v * v : 0.0f;
    __shared__ float sd[256];
    sd[t] = x2;
    __syncthreads();
    if (t < 64) {
        float s = sd[t] + sd[t + 64] + sd[t + 128] + sd[t + 192];
        if (s != 0.0f) atomicAdd(&cnss[(g + 1) * 64 + t], s);
    }
}

// cu (item rows, 4-view row-norm fusion) + ci (user rows, 4-view col-norm fusion)
__global__ void k_cuci(const float* __restrict__ embf, const float* __restrict__ out2,
                       const float* __restrict__ cnss, float* __restrict__ cu,
                       float* __restrict__ ci) {
    int b = blockIdx.x, l = threadIdx.x;
    if (b < 448) {
        if (b >= NITEM) { cu[(size_t)b * DD + l] = 0.0f; return; }
        int node = NUSER + b;
        const float* v0 = embf + (size_t)node * DD;
        const float* v1 = out2 + (size_t)node * DD;
        const float* v2 = out2 + OUT2STRIDE + (size_t)node * DD;
        const float* v3 = out2 + 2ull * OUT2STRIDE + (size_t)node * DD;
        float total = 0.0f;
        { float x = v0[l]; float ss = wsum(x * x); total += x / sqrtf(ss); }
        { float x = v1[l]; float ss = wsum(x * x); total += x / sqrtf(ss); }
        { float x = v2[l]; float ss = wsum(x * x); total += x / sqrtf(ss); }
        { float x = v3[l]; float ss = wsum(x * x); total += x / sqrtf(ss); }
        cu[(size_t)b * DD + l] = 0.25f * total;
    } else {
        int u = b - 448;
        size_t i = (size_t)u * DD + l;
        float s = embf[i] / sqrtf(cnss[l])
                + out2[i] / sqrtf(cnss[64 + l])
                + out2[OUT2STRIDE + i] / sqrtf(cnss[128 + l])
                + out2[2ull * OUT2STRIDE + i] / sqrtf(cnss[192 + l]);
        ci[i] = 0.25f * s;
    }
}

// e_synd = (presc @ c_u)/rowsum; h_pre = e_synd @ mlpW^T + b; + BN partial sums
__global__ __launch_bounds__(256) void k_esynd(const void* __restrict__ presc,
        const float* __restrict__ cu, const float* __restrict__ mlpW,
        const float* __restrict__ mlpB, const int* __restrict__ flag,
        float* __restrict__ hpre, float* __restrict__ bnsum) {
    int t = threadIdx.x, w = t >> 6, l = t & 63;
    int b0 = blockIdx.x * 16 + w * 4;
    int isbf = *flag;
    const __hip_bfloat16* pB = (const __hip_bfloat16*)presc;
    const float* pF = (const float*)presc;
    float acc[4] = {0, 0, 0, 0}, ps[4] = {0, 0, 0, 0};
    for (int j0 = 0; j0 < NITEM; j0 += 64) {
        int j = j0 + l;
        float pv[4];
#pragma unroll
        for (int r = 0; r < 4; ++r) {
            float v = 0.0f;
            if (j < NITEM) {
                size_t idx = (size_t)(b0 + r) * NITEM + j;
                v = isbf ? __bfloat162float(pB[idx]) : pF[idx];
            }
            pv[r] = v; ps[r] += v;
        }
#pragma unroll 16
        for (int jj = 0; jj < 64; ++jj) {
            float cv = cu[(size_t)(j0 + jj) * DD + l];
#pragma unroll
            for (int r = 0; r < 4; ++r)
                acc[r] = fmaf(__shfl(pv[r], jj, 64), cv, acc[r]);
        }
    }
    float e[4];
#pragma unroll
    for (int r = 0; r < 4; ++r) e[r] = acc[r] / wsum(ps[r]);
    float bb = mlpB[l];
    float h[4] = {bb, bb, bb, bb};
    for (int k = 0; k < 64; ++k) {
        float wv = mlpW[l * 64 + k];
#pragma unroll
        for (int r = 0; r < 4; ++r)
            h[r] = fmaf(__shfl(e[r], k, 64), wv, h[r]);
    }
    float s1 = 0.0f, s2 = 0.0f;
#pragma unroll
    for (int r = 0; r < 4; ++r) {
        hpre[(size_t)(b0 + r) * DD + l] = h[r];
        s1 += h[r]; s2 = fmaf(h[r], h[r], s2);
    }
    __shared__ float l1[4][64], l2[4][64];
    l1[w][l] = s1; l2[w][l] = s2;
    __syncthreads();
    if (w == 0) {
        float a = l1[0][l] + l1[1][l] + l1[2][l] + l1[3][l];
        float c = l2[0][l] + l2[1][l] + l2[2][l] + l2[3][l];
        atomicAdd(&bnsum[l], a);
        atomicAdd(&bnsum[64 + l], c);
    }
}

// pre[b][u] = relu(BN(h_pre[b])) . c_i[u]; BN finalized from bnsum
__global__ __launch_bounds__(256) void k_final(const float* __restrict__ hpre,
        const float* __restrict__ bnsum, const float* __restrict__ gamma,
        const float* __restrict__ beta, const float* __restrict__ ci,
        void* __restrict__ out, const int* __restrict__ flag) {
    int b0 = blockIdx.x * 8;
    int t = threadIdx.x;
    int isbf = *flag;
    __shared__ float mn[64], rs[64];
    __shared__ float hs[8][64];
    __shared__ float cs[64 * 65];
    if (t < 64) {
        float mean = bnsum[t] * (1.0f / BB);
        float var = bnsum[64 + t] * (1.0f / BB) - mean * mean;
        mn[t] = mean;
        rs[t] = 1.0f / sqrtf(var + 1e-5f);
    }
    __syncthreads();
    for (int i = t; i < 8 * 64; i += 256) {
        int r = i / 64, d = i % 64;
        float v = hpre[(size_t)(b0 + r) * DD + d];
        v = (v - mn[d]) * rs[d] * gamma[d] + beta[d];
        hs[r][d] = fmaxf(v, 0.0f);
    }
    int cc = t % 64;
    int rsx = t / 64;
    for (int ct = 0; ct < 13; ++ct) {
        __syncthreads();
        for (int i = t; i < 64 * 64; i += 256) {
            int c = i / 64, d = i % 64;
            int col = ct * 64 + c;
            cs[c * 65 + d] = (col < NUSER) ? ci[(size_t)col * DD + d] : 0.0f;
        }
        __syncthreads();
        float a0 = 0.0f, a1 = 0.0f;
#pragma unroll
        for (int d = 0; d < 64; ++d) {
            float cv = cs[cc * 65 + d];
            a0 = fmaf(hs[rsx][d], cv, a0);
            a1 = fmaf(hs[rsx + 4][d], cv, a1);
        }
        int col = ct * 64 + cc;
        if (col < NUSER) {
            size_t o0 = (size_t)(b0 + rsx) * NUSER + col;
            size_t o1 = (size_t)(b0 + rsx + 4) * NUSER + col;
            if (isbf) {
                ((__hip_bfloat16*)out)[o0] = __float2bfloat16(a0);
                ((__hip_bfloat16*)out)[o1] = __float2bfloat16(a1);
            } else {
                ((float*)out)[o0] = a0;
                ((float*)out)[o1] = a1;
            }
        }
    }
}

extern "C" void kernel_launch(void* const* d_in, const int* in_sizes, int n_in,
                              void* d_out, int out_size, void* d_ws, size_t ws_size,
                              hipStream_t stream) {
    const void* presc = d_in[1];
    const void* emb   = d_in[2];
    const void* W1    = d_in[3];
    const void* b1    = d_in[4];
    const void* W2    = d_in[5];
    const void* b2    = d_in[6];
    const void* mlpW  = d_in[7];
    const void* mlpB  = d_in[8];
    const void* gamma = d_in[9];
    const void* beta  = d_in[10];
    const int* tg = (const int*)d_in[11];
    const int* s1 = (const int*)d_in[12];
    const int* s2 = (const int*)d_in[13];
    float* ws = (float*)d_ws;
    (void)in_sizes; (void)n_in; (void)out_size;

    float* bnsum = ws + OFF_BNS;
    float* cnss  = ws + OFF_CNSS;
    int*   flag  = (int*)(ws + OFF_FLAG);
    float* cvt   = ws + OFF_CVT;
    float* embF  = cvt + CVT_EMB;
    float* W1F   = cvt + CVT_W1;
    float* b1F   = cvt + CVT_B1;
    float* W2F   = cvt + CVT_W2;
    float* b2F   = cvt + CVT_B2;
    float* mlpWF = cvt + CVT_MLPW;
    float* mlpBF = cvt + CVT_MLPB;
    float* gamF  = cvt + CVT_GAMMA;
    float* betF  = cvt + CVT_BETA;
    u16*   Abf   = (u16*)(ws + OFF_ABF);
    float* rcnt  = ws + OFF_RC;
    uint*  P8    = (uint*)(ws + OFF_POOL);
    float* part  = ws + OFF_PART;
    u16*   H1hi  = (u16*)(ws + OFF_H1);
    u16*   H1lo  = H1hi + 64ull * NPAD;
    u16*   H2hi  = (u16*)(ws + OFF_H2);
    u16*   H2lo  = H2hi + 3ull * 64 * NPAD;
    float* out2  = ws + OFF_OUT2;
    float* cu    = ws + OFF_CU;
    float* ci    = ws + OFF_CI;
    float* hpre  = ws + OFF_H;

    // choose S (edge-slice count / partial copies) by workspace headroom
    size_t p8per = 3ull * NN * P8W;        // floats (==u32) per partial copy
    int S = 4;
    if      (ws_size >= (OFF_POOL + 16ull * p8per) * 4) S = 16;
    else if (ws_size >= (OFF_POOL +  8ull * p8per) * 4) S = 8;

    hipMemsetAsync(ws, 0, MEMSET_FLOATS * sizeof(float), stream);   // bnsum + cnss
    k_cvt_all<<<CVT_TOTAL / 256, 256, 0, stream>>>(
        presc, emb, W1, b1, W2, b2, mlpW, mlpB, gamma, beta, cvt, cnss, flag);

    k_histp<<<3 * RB * S, 512, 0, stream>>>(tg, s1, s2, P8, S);
    k_abfrc<<<3 * NN, 256, 0, stream>>>(P8, S, Abf, rcnt);

    // layer 1
    k_xf<<<MT, 256, 0, stream>>>(embF, 0, nullptr, nullptr, 0, W1F, b1F, H1hi, H1lo, 0);
    k_aggp<<<3 * MT * KT, 256, 0, stream>>>(Abf, H1hi, H1lo, 0, part);
    // layer 2
    k_xf<<<3 * MT, 256, 0, stream>>>(nullptr, 0, part, rcnt, 1, W2F, b2F, H2hi, H2lo, 64ull * NPAD);
    k_aggp<<<3 * MT * KT, 256, 0, stream>>>(Abf, H2hi, H2lo, 64ull * NPAD, part);
    k_comb<<<3 * CPG, 256, 0, stream>>>(part, rcnt, out2, cnss);

    // view fusion
    k_cuci<<<448 + NUSER, 64, 0, stream>>>(embF, out2, cnss, cu, ci);

    // pooling + MLP(+BN partials) + final
    k_esynd<<<BB / 16, 256, 0, stream>>>(presc, cu, mlpWF, mlpBF, flag, hpre, bnsum);
    k_final<<<BB / 8, 256, 0, stream>>>(hpre, bnsum, gamF, betF, ci, d_out, flag);
}

// Round 3
// 281.979 us; speedup vs baseline: 1.3653x; 1.2131x over previous
//
#include <hip/hip_runtime.h>
#include <hip/hip_bf16.h>

// R3: k_final rewritten as MFMA tile-GEMM. Old k_final was 67us at 1 wave/SIMD
// (grid 256, occupancy 10.6%, VALUBusy 7.4%): 13 barrier-separated LDS stagings
// serialized with zero latency hiding, for a 211-MFLOP GEMM whose roofline is
// ~2us. New: 64x64 tiles, BN+relu fused into A staging, bf16 hi/lo split both
// operands (hh+hl+lh), fragment layout copied verbatim from k_aggp. Grid 416.

#define NN    1195
#define NUSER 805
#define NITEM 390
#define DD    64
#define BB    2048
#define NPAD  1216          // 19*64, padded node/k count
#define E_TOT 1000000
#define E_SUB 500000
#define MT    19            // m-tiles per graph
#define KT    8             // K-split factor
#define CHUNK 3             // ceil(19/8) k-subtiles per block
#define LSTR  72            // LDS row stride in bf16 elems
#define OUT2STRIDE (NN*DD)
#define CPG    299          // comb blocks per graph = ceil(1195*64/256)
#define P8W    152          // u32 words per histogram row (1216 u4 cells)
#define ROWS   96           // histogram rows per block (57KB LDS)
#define RB     13           // ceil(NN/ROWS)
#define FNT    13           // k_final col tiles = ceil(805/64)

typedef unsigned int uint;
typedef unsigned short u16;
typedef unsigned char u8;
typedef __attribute__((ext_vector_type(8))) short short8;
typedef __attribute__((ext_vector_type(4))) float f32x4;

__device__ __forceinline__ float wsum(float v) {
#pragma unroll
    for (int m = 32; m > 0; m >>= 1) v += __shfl_xor(v, m, 64);
    return v;
}
__device__ __forceinline__ u16 f2b(float f) {           // fp32 -> bf16 RNE bits
    uint u = __float_as_uint(f);
    return (u16)((u + 0x7FFFu + ((u >> 16) & 1u)) >> 16);
}
__device__ __forceinline__ float b2f16(u16 b) { return __uint_as_float(((uint)b) << 16); }

// ---- converted-input layout (floats, relative to OFF_CVT) ----
#define CVT_EMB   0
#define CVT_W1    76480
#define CVT_B1    80576
#define CVT_W2    80640
#define CVT_B2    84736
#define CVT_MLPW  84800
#define CVT_MLPB  88896
#define CVT_GAMMA 88960
#define CVT_BETA  89024
#define CVT_TOTAL 89088

// ---------------- workspace layout (floats) ----------------
constexpr size_t alignUp64(size_t x) { return (x + 63) & ~size_t(63); }
constexpr size_t OFF_BNS  = 0;                                        // [128]
constexpr size_t OFF_CNSS = 128;                                      // [256]
constexpr size_t MEMSET_FLOATS = 384;                                 // zeroed region
constexpr size_t OFF_FLAG = 384;                                      // [16]
constexpr size_t OFF_CVT  = 448;                                      // [CVT_TOTAL]
constexpr size_t OFF_ABF  = alignUp64(OFF_CVT + CVT_TOTAL);           // bf16 A 3*NN*NPAD u16
constexpr size_t OFF_RC   = alignUp64(OFF_ABF + (3ull * NN * NPAD) / 2);
constexpr size_t OFF_POOL = alignUp64(OFF_RC + 3ull * NPAD);
constexpr size_t OFF_PART = OFF_POOL;                                 // fp32 partials KT*3*NPAD*64
constexpr size_t OFF_H1   = alignUp64(OFF_PART + (size_t)KT * 3 * NPAD * 64);
constexpr size_t OFF_H2   = alignUp64(OFF_H1 + 64ull * NPAD);
constexpr size_t OFF_OUT2 = alignUp64(OFF_H2 + 3ull * 64 * NPAD);
constexpr size_t OFF_CU   = alignUp64(OFF_OUT2 + 3ull * NN * DD);     // [448*64]
constexpr size_t OFF_CI   = alignUp64(OFF_CU + 448ull * DD);
constexpr size_t OFF_H    = alignUp64(OFF_CI + (size_t)NUSER * DD);
constexpr size_t POOL_END = alignUp64(OFF_H + (size_t)BB * DD);

// ---------------- kernels ----------------

// convert small float inputs to fp32, detect dtype, accumulate view-0 user col-sumsq
__global__ __launch_bounds__(256) void k_cvt_all(const void* presc,
        const void* p1, const void* p2, const void* p3, const void* p4,
        const void* p5, const void* p6, const void* p7, const void* p8, const void* p9,
        float* __restrict__ dst, float* __restrict__ cnss, int* __restrict__ flag) {
    int isbf = (((const u16*)presc)[0] == 0x3F80u) ? 1 : 0;   // presc[0][0]==1.0 always
    int t = threadIdx.x;
    int i = blockIdx.x * 256 + t;
    if (i == 0) *flag = isbf;
    const void* s2; int o2;
    if      (i < CVT_W1)    { s2 = p1; o2 = i; }
    else if (i < CVT_B1)    { s2 = p2; o2 = i - CVT_W1; }
    else if (i < CVT_W2)    { s2 = p3; o2 = i - CVT_B1; }
    else if (i < CVT_B2)    { s2 = p4; o2 = i - CVT_W2; }
    else if (i < CVT_MLPW)  { s2 = p5; o2 = i - CVT_B2; }
    else if (i < CVT_MLPB)  { s2 = p6; o2 = i - CVT_MLPW; }
    else if (i < CVT_GAMMA) { s2 = p7; o2 = i - CVT_MLPB; }
    else if (i < CVT_BETA)  { s2 = p8; o2 = i - CVT_GAMMA; }
    else                    { s2 = p9; o2 = i - CVT_BETA; }
    float v = isbf ? __bfloat162float(((const __hip_bfloat16*)s2)[o2])
                   : ((const float*)s2)[o2];
    dst[i] = v;
    // view-0 column sumsq over user rows of emb (emb occupies i < 76480, 64 dims/row)
    float x2 = (i < NUSER * 64) ? v * v : 0.0f;
    __shared__ float sd[256];
    sd[t] = x2;
    __syncthreads();
    if (t < 64 && blockIdx.x * 256 < NUSER * 64) {
        float s = sd[t] + sd[t + 64] + sd[t + 128] + sd[t + 192];
        if (s != 0.0f) atomicAdd(&cnss[t], s);
    }
}

// LDS-bucketed u4 partial histograms.
__global__ __launch_bounds__(512) void k_histp(const int* __restrict__ tg,
        const int* __restrict__ s1, const int* __restrict__ s2,
        uint* __restrict__ P8, int S) {
    __shared__ __align__(16) uint lds[ROWS * P8W];
    int b = blockIdx.x;
    int p = b % S;
    int rg = b / S;
    int r = rg % RB;
    int g = rg / RB;
    int r0 = r * ROWS;
    int t = threadIdx.x;

    {
        uint4* l4 = (uint4*)lds;
        for (int i = t; i < (ROWS * P8W) >> 2; i += 512) l4[i] = (uint4){0u, 0u, 0u, 0u};
    }
    __syncthreads();

    const int* eg = (g == 0) ? tg : (g == 1 ? s1 : s2);
    int Eg = (g == 0) ? E_TOT : E_SUB;
    int e0 = (int)(((long)p * Eg / S) & ~3L);
    int e1 = (p == S - 1) ? Eg : (int)(((long)(p + 1) * Eg / S) & ~3L);
    const int* srcp = eg;
    const int* dstp = eg + Eg;
    for (int i = e0 + t * 4; i < e1; i += 512 * 4) {
        int4 d4 = *(const int4*)(dstp + i);
        int4 s4 = *(const int4*)(srcp + i);
        int rw;
        rw = d4.x - r0; if ((unsigned)rw < ROWS) atomicAdd(&lds[rw * P8W + (s4.x >> 3)], 1u << ((s4.x & 7) * 4));
        rw = d4.y - r0; if ((unsigned)rw < ROWS) atomicAdd(&lds[rw * P8W + (s4.y >> 3)], 1u << ((s4.y & 7) * 4));
        rw = d4.z - r0; if ((unsigned)rw < ROWS) atomicAdd(&lds[rw * P8W + (s4.z >> 3)], 1u << ((s4.z & 7) * 4));
        rw = d4.w - r0; if ((unsigned)rw < ROWS) atomicAdd(&lds[rw * P8W + (s4.w >> 3)], 1u << ((s4.w & 7) * 4));
    }
    __syncthreads();

    int rmax = ROWS; if (r0 + rmax > NN) rmax = NN - r0;
    uint* out = P8 + ((size_t)p * 3 + g) * NN * P8W + (size_t)r0 * P8W;
    int n4 = (rmax * P8W) >> 2;
    const uint4* l4 = (const uint4*)lds;
    uint4* o4 = (uint4*)out;
    for (int i = t; i < n4; i += 512) o4[i] = l4[i];
}

// merge S u4 partial copies -> bf16 A row (pad cols zero) + reciprocal in-degree
__global__ __launch_bounds__(256) void k_abfrc(const uint* __restrict__ P8, int S,
        u16* __restrict__ Abf, float* __restrict__ rcnt) {
    int row = blockIdx.x;            // 0..3*NN-1
    int g = row / NN, m = row % NN;
    int t = threadIdx.x, w = t >> 6;
    float partial = 0.0f;
    if (t < P8W) {
        uint cnt[8] = {0, 0, 0, 0, 0, 0, 0, 0};
        for (int p = 0; p < S; ++p) {
            uint v = P8[(((size_t)p * 3 + g) * NN + m) * P8W + t];
#pragma unroll
            for (int k = 0; k < 8; ++k) cnt[k] += (v >> (4 * k)) & 15u;
        }
        uint4 o;
        o.x = (uint)f2b((float)cnt[0]) | ((uint)f2b((float)cnt[1]) << 16);
        o.y = (uint)f2b((float)cnt[2]) | ((uint)f2b((float)cnt[3]) << 16);
        o.z = (uint)f2b((float)cnt[4]) | ((uint)f2b((float)cnt[5]) << 16);
        o.w = (uint)f2b((float)cnt[6]) | ((uint)f2b((float)cnt[7]) << 16);
        *(uint4*)(Abf + (size_t)row * NPAD + t * 8) = o;
#pragma unroll
        for (int k = 0; k < 8; ++k) partial += (float)cnt[k];
    }
    partial = wsum(partial);
    __shared__ float ws4[4];
    if ((t & 63) == 0) ws4[w] = partial;
    __syncthreads();
    if (t == 0)
        rcnt[g * NPAD + m] = 1.0f / fmaxf(ws4[0] + ws4[1] + ws4[2] + ws4[3], 1.0f);
}

// Linear transform -> transposed bf16 hi/lo planes [g][64 dims][NPAD nodes].
__global__ __launch_bounds__(256) void k_xf(const float* __restrict__ x, size_t xgstride,
        const float* __restrict__ part, const float* __restrict__ rcnt, int fromPart,
        const float* __restrict__ W, const float* __restrict__ bias,
        u16* __restrict__ Hhi, u16* __restrict__ Hlo, size_t hgstride) {
    int b = blockIdx.x;
    int g = b / MT, nt = b % MT;
    int t = threadIdx.x, w = t >> 6, l = t & 63;
    int n0 = nt * 64;
    __shared__ float Ws[64 * 65];
    __shared__ float bs[64];
    __shared__ float Ts[64 * 68];
    for (int i = t; i < 4096; i += 256) Ws[(i >> 6) * 65 + (i & 63)] = W[i];
    if (t < 64) bs[t] = bias[t];
    float xr[16];
#pragma unroll
    for (int i = 0; i < 16; ++i) {
        int node = n0 + w * 16 + i;
        float v = 0.0f;
        if (node < NN) {
            if (fromPart) {
                float s = 0.0f;
#pragma unroll
                for (int k = 0; k < KT; ++k)
                    s += part[(((size_t)k * 3 + g) * NPAD + node) * 64 + l];
                v = tanhf(s * rcnt[g * NPAD + node]);
            } else {
                v = x[xgstride * g + (size_t)node * 64 + l];
            }
        }
        xr[i] = v;
    }
    __syncthreads();
#pragma unroll
    for (int i = 0; i < 16; ++i) {
        int node = n0 + w * 16 + i;
        float acc = 0.0f;
        if (node < NN) {
            acc = bs[l];
#pragma unroll
            for (int k = 0; k < 64; ++k)
                acc = fmaf(__shfl(xr[i], k, 64), Ws[l * 65 + k], acc);
        }
        Ts[l * 68 + w * 16 + i] = acc;
    }
    __syncthreads();
    int d = t >> 2, seg = t & 3;
    u16 hb[16], lb[16];
#pragma unroll
    for (int j = 0; j < 16; ++j) {
        float v = Ts[d * 68 + seg * 16 + j];
        u16 h = f2b(v);
        hb[j] = h;
        lb[j] = f2b(v - b2f16(h));
    }
    size_t base = hgstride * g + (size_t)d * NPAD + n0 + seg * 16;
#pragma unroll
    for (int j = 0; j < 4; ++j) {
        uint2 ph, pl;
        ph.x = (uint)hb[j*4]   | ((uint)hb[j*4+1] << 16);
        ph.y = (uint)hb[j*4+2] | ((uint)hb[j*4+3] << 16);
        pl.x = (uint)lb[j*4]   | ((uint)lb[j*4+1] << 16);
        pl.y = (uint)lb[j*4+2] | ((uint)lb[j*4+3] << 16);
        *(uint2*)(Hhi + base + j*4) = ph;
        *(uint2*)(Hlo + base + j*4) = pl;
    }
}

// MFMA aggregation with split-bf16 B; K-split partials
__global__ __launch_bounds__(256) void k_aggp(const u16* __restrict__ Abf,
        const u16* __restrict__ Hhi, const u16* __restrict__ Hlo, size_t hstride,
        float* __restrict__ part) {
    int b = blockIdx.x;
    int kt = b & 7;
    int mt = (b >> 3) % MT;
    int g  = (b >> 3) / MT;
    int t = threadIdx.x, w = t >> 6, l = t & 63;
    __shared__ u16 As[64 * LSTR], Bh[64 * LSTR], Bl[64 * LSTR];
    f32x4 acc[4];
#pragma unroll
    for (int p = 0; p < 4; ++p) acc[p] = (f32x4){0.f, 0.f, 0.f, 0.f};
    int m0 = mt * 64;
    const u16* Ag = Abf + (size_t)g * NN * NPAD;
    const u16* Hg = Hhi + hstride * g;
    const u16* Lg = Hlo + hstride * g;
    int st0 = kt * CHUNK;
    int st1 = st0 + CHUNK; if (st1 > MT) st1 = MT;
    int rr = t >> 4, c4 = (t & 15) * 4;
    for (int st = st0; st < st1; ++st) {
        int s0 = st * 64;
        __syncthreads();
#pragma unroll
        for (int pass = 0; pass < 4; ++pass) {
            int r = pass * 16 + rr;
            uint2 av = {0u, 0u};
            if (m0 + r < NN) av = *(const uint2*)(Ag + (size_t)(m0 + r) * NPAD + s0 + c4);
            *(uint2*)(As + r * LSTR + c4) = av;
            *(uint2*)(Bh + r * LSTR + c4) = *(const uint2*)(Hg + (size_t)r * NPAD + s0 + c4);
            *(uint2*)(Bl + r * LSTR + c4) = *(const uint2*)(Lg + (size_t)r * NPAD + s0 + c4);
        }
        __syncthreads();
        int mrow = w * 16 + (l & 15);
        int q8 = (l >> 4) * 8;
#pragma unroll
        for (int ks = 0; ks < 2; ++ks) {
            short8 a = *(const short8*)(As + mrow * LSTR + ks * 32 + q8);
#pragma unroll
            for (int p = 0; p < 4; ++p) {
                int nrow = p * 16 + (l & 15);
                short8 bh = *(const short8*)(Bh + nrow * LSTR + ks * 32 + q8);
                short8 bl = *(const short8*)(Bl + nrow * LSTR + ks * 32 + q8);
                acc[p] = __builtin_amdgcn_mfma_f32_16x16x32_bf16(a, bh, acc[p], 0, 0, 0);
                acc[p] = __builtin_amdgcn_mfma_f32_16x16x32_bf16(a, bl, acc[p], 0, 0, 0);
            }
        }
    }
    int q = l >> 4;
#pragma unroll
    for (int p = 0; p < 4; ++p) {
        int n = p * 16 + (l & 15);
#pragma unroll
        for (int r = 0; r < 4; ++r) {
            int m = m0 + w * 16 + q * 4 + r;
            if (m < NN)
                part[(((size_t)kt * 3 + g) * NPAD + m) * 64 + n] = acc[p][r];
        }
    }
}

// layer-2 combine + views-1..3 user column sumsq accumulation
__global__ __launch_bounds__(256) void k_comb(const float* __restrict__ part,
        const float* __restrict__ rcnt, float* __restrict__ out, float* __restrict__ cnss) {
    int g = blockIdx.x / CPG, bi = blockIdx.x % CPG;
    int t = threadIdx.x;
    int idx = bi * 256 + t;                 // within graph
    int m = idx >> 6, n = idx & 63;
    bool valid = idx < NN * 64;
    float v = 0.0f;
    if (valid) {
        float s = 0.0f;
#pragma unroll
        for (int k = 0; k < KT; ++k)
            s += part[(((size_t)k * 3 + g) * NPAD + m) * 64 + n];
        v = tanhf(s * rcnt[g * NPAD + m]);
        out[(size_t)g * NN * 64 + idx] = v;
    }
    float x2 = (valid && m < NUSER) ? v * v : 0.0f;
    __shared__ float sd[256];
    sd[t] = x2;
    __syncthreads();
    if (t < 64) {
        float s = sd[t] + sd[t + 64] + sd[t + 128] + sd[t + 192];
        if (s != 0.0f) atomicAdd(&cnss[(g + 1) * 64 + t], s);
    }
}

// cu (item rows, 4-view row-norm fusion) + ci (user rows, 4-view col-norm fusion)
__global__ void k_cuci(const float* __restrict__ embf, const float* __restrict__ out2,
                       const float* __restrict__ cnss, float* __restrict__ cu,
                       float* __restrict__ ci) {
    int b = blockIdx.x, l = threadIdx.x;
    if (b < 448) {
        if (b >= NITEM) { cu[(size_t)b * DD + l] = 0.0f; return; }
        int node = NUSER + b;
        const float* v0 = embf + (size_t)node * DD;
        const float* v1 = out2 + (size_t)node * DD;
        const float* v2 = out2 + OUT2STRIDE + (size_t)node * DD;
        const float* v3 = out2 + 2ull * OUT2STRIDE + (size_t)node * DD;
        float total = 0.0f;
        { float x = v0[l]; float ss = wsum(x * x); total += x / sqrtf(ss); }
        { float x = v1[l]; float ss = wsum(x * x); total += x / sqrtf(ss); }
        { float x = v2[l]; float ss = wsum(x * x); total += x / sqrtf(ss); }
        { float x = v3[l]; float ss = wsum(x * x); total += x / sqrtf(ss); }
        cu[(size_t)b * DD + l] = 0.25f * total;
    } else {
        int u = b - 448;
        size_t i = (size_t)u * DD + l;
        float s = embf[i] / sqrtf(cnss[l])
                + out2[i] / sqrtf(cnss[64 + l])
                + out2[OUT2STRIDE + i] / sqrtf(cnss[128 + l])
                + out2[2ull * OUT2STRIDE + i] / sqrtf(cnss[192 + l]);
        ci[i] = 0.25f * s;
    }
}

// e_synd = (presc @ c_u)/rowsum; h_pre = e_synd @ mlpW^T + b; + BN partial sums
__global__ __launch_bounds__(256) void k_esynd(const void* __restrict__ presc,
        const float* __restrict__ cu, const float* __restrict__ mlpW,
        const float* __restrict__ mlpB, const int* __restrict__ flag,
        float* __restrict__ hpre, float* __restrict__ bnsum) {
    int t = threadIdx.x, w = t >> 6, l = t & 63;
    int b0 = blockIdx.x * 16 + w * 4;
    int isbf = *flag;
    const __hip_bfloat16* pB = (const __hip_bfloat16*)presc;
    const float* pF = (const float*)presc;
    float acc[4] = {0, 0, 0, 0}, ps[4] = {0, 0, 0, 0};
    for (int j0 = 0; j0 < NITEM; j0 += 64) {
        int j = j0 + l;
        float pv[4];
#pragma unroll
        for (int r = 0; r < 4; ++r) {
            float v = 0.0f;
            if (j < NITEM) {
                size_t idx = (size_t)(b0 + r) * NITEM + j;
                v = isbf ? __bfloat162float(pB[idx]) : pF[idx];
            }
            pv[r] = v; ps[r] += v;
        }
#pragma unroll 16
        for (int jj = 0; jj < 64; ++jj) {
            float cv = cu[(size_t)(j0 + jj) * DD + l];
#pragma unroll
            for (int r = 0; r < 4; ++r)
                acc[r] = fmaf(__shfl(pv[r], jj, 64), cv, acc[r]);
        }
    }
    float e[4];
#pragma unroll
    for (int r = 0; r < 4; ++r) e[r] = acc[r] / wsum(ps[r]);
    float bb = mlpB[l];
    float h[4] = {bb, bb, bb, bb};
    for (int k = 0; k < 64; ++k) {
        float wv = mlpW[l * 64 + k];
#pragma unroll
        for (int r = 0; r < 4; ++r)
            h[r] = fmaf(__shfl(e[r], k, 64), wv, h[r]);
    }
    float s1 = 0.0f, s2 = 0.0f;
#pragma unroll
    for (int r = 0; r < 4; ++r) {
        hpre[(size_t)(b0 + r) * DD + l] = h[r];
        s1 += h[r]; s2 = fmaf(h[r], h[r], s2);
    }
    __shared__ float l1[4][64], l2[4][64];
    l1[w][l] = s1; l2[w][l] = s2;
    __syncthreads();
    if (w == 0) {
        float a = l1[0][l] + l1[1][l] + l1[2][l] + l1[3][l];
        float c = l2[0][l] + l2[1][l] + l2[2][l] + l2[3][l];
        atomicAdd(&bnsum[l], a);
        atomicAdd(&bnsum[64 + l], c);
    }
}

// pre = relu(BN(h_pre)) @ ci^T via MFMA 64x64 tiles, bf16 hi/lo both operands.
// Fragment layout identical to k_aggp (harness-verified).
__global__ __launch_bounds__(256) void k_final(const float* __restrict__ hpre,
        const float* __restrict__ bnsum, const float* __restrict__ gamma,
        const float* __restrict__ beta, const float* __restrict__ ci,
        void* __restrict__ out, const int* __restrict__ flag) {
    int b = blockIdx.x;
    int mt = b / FNT, nt = b % FNT;
    int m0 = mt * 64, n0 = nt * 64;
    int t = threadIdx.x, w = t >> 6, l = t & 63;
    __shared__ u16 Ah[64 * LSTR], Al[64 * LSTR], Bh[64 * LSTR], Bl[64 * LSTR];
    __shared__ float mn[64], rsg[64], bt[64];
    if (t < 64) {
        float mean = bnsum[t] * (1.0f / BB);
        float var = bnsum[64 + t] * (1.0f / BB) - mean * mean;
        mn[t] = mean;
        rsg[t] = gamma[t] / sqrtf(var + 1e-5f);
        bt[t] = beta[t];
    }
    __syncthreads();
    // stage A: hpre 64x64 tile, fused BN+relu, split bf16 hi/lo
    const float4* hp4 = (const float4*)(hpre + (size_t)m0 * 64);
    const float4* ci4 = (const float4*)ci;
#pragma unroll
    for (int k = 0; k < 4; ++k) {
        int i = t + k * 256;                 // float4 index in 64x16 tile
        int r = i >> 4, c4 = (i & 15) * 4;
        float4 v = hp4[i];
        float vv[4] = {v.x, v.y, v.z, v.w};
        u16 hh[4], ll[4];
#pragma unroll
        for (int j = 0; j < 4; ++j) {
            int d = c4 + j;
            float x = fmaxf((vv[j] - mn[d]) * rsg[d] + bt[d], 0.0f);
            u16 hb = f2b(x);
            hh[j] = hb;
            ll[j] = f2b(x - b2f16(hb));
        }
        uint2 ph, pl;
        ph.x = (uint)hh[0] | ((uint)hh[1] << 16);
        ph.y = (uint)hh[2] | ((uint)hh[3] << 16);
        pl.x = (uint)ll[0] | ((uint)ll[1] << 16);
        pl.y = (uint)ll[2] | ((uint)ll[3] << 16);
        *(uint2*)(Ah + r * LSTR + c4) = ph;
        *(uint2*)(Al + r * LSTR + c4) = pl;
        // stage B: ci 64x64 tile (rows = output cols), zero-pad past NUSER
        int col = n0 + r;
        float4 cv = (col < NUSER) ? ci4[(size_t)col * 16 + (i & 15)]
                                  : (float4){0.f, 0.f, 0.f, 0.f};
        float cc[4] = {cv.x, cv.y, cv.z, cv.w};
#pragma unroll
        for (int j = 0; j < 4; ++j) {
            u16 hb = f2b(cc[j]);
            hh[j] = hb;
            ll[j] = f2b(cc[j] - b2f16(hb));
        }
        ph.x = (uint)hh[0] | ((uint)hh[1] << 16);
        ph.y = (uint)hh[2] | ((uint)hh[3] << 16);
        pl.x = (uint)ll[0] | ((uint)ll[1] << 16);
        pl.y = (uint)ll[2] | ((uint)ll[3] << 16);
        *(uint2*)(Bh + r * LSTR + c4) = ph;
        *(uint2*)(Bl + r * LSTR + c4) = pl;
    }
    __syncthreads();
    f32x4 acc[4];
#pragma unroll
    for (int p = 0; p < 4; ++p) acc[p] = (f32x4){0.f, 0.f, 0.f, 0.f};
    int mrow = w * 16 + (l & 15);
    int q8 = (l >> 4) * 8;
#pragma unroll
    for (int ks = 0; ks < 2; ++ks) {
        short8 ah = *(const short8*)(Ah + mrow * LSTR + ks * 32 + q8);
        short8 al = *(const short8*)(Al + mrow * LSTR + ks * 32 + q8);
#pragma unroll
        for (int p = 0; p < 4; ++p) {
            int nrow = p * 16 + (l & 15);
            short8 bh = *(const short8*)(Bh + nrow * LSTR + ks * 32 + q8);
            short8 bl = *(const short8*)(Bl + nrow * LSTR + ks * 32 + q8);
            acc[p] = __builtin_amdgcn_mfma_f32_16x16x32_bf16(ah, bh, acc[p], 0, 0, 0);
            acc[p] = __builtin_amdgcn_mfma_f32_16x16x32_bf16(ah, bl, acc[p], 0, 0, 0);
            acc[p] = __builtin_amdgcn_mfma_f32_16x16x32_bf16(al, bh, acc[p], 0, 0, 0);
        }
    }
    int isbf = *flag;
    int q = l >> 4;
#pragma unroll
    for (int p = 0; p < 4; ++p) {
        int col = n0 + p * 16 + (l & 15);
        if (col < NUSER) {
#pragma unroll
            for (int r = 0; r < 4; ++r) {
                int row = m0 + w * 16 + q * 4 + r;
                size_t o = (size_t)row * NUSER + col;
                if (isbf) ((__hip_bfloat16*)out)[o] = __float2bfloat16(acc[p][r]);
                else      ((float*)out)[o] = acc[p][r];
            }
        }
    }
}

extern "C" void kernel_launch(void* const* d_in, const int* in_sizes, int n_in,
                              void* d_out, int out_size, void* d_ws, size_t ws_size,
                              hipStream_t stream) {
    const void* presc = d_in[1];
    const void* emb   = d_in[2];
    const void* W1    = d_in[3];
    const void* b1    = d_in[4];
    const void* W2    = d_in[5];
    const void* b2    = d_in[6];
    const void* mlpW  = d_in[7];
    const void* mlpB  = d_in[8];
    const void* gamma = d_in[9];
    const void* beta  = d_in[10];
    const int* tg = (const int*)d_in[11];
    const int* s1 = (const int*)d_in[12];
    const int* s2 = (const int*)d_in[13];
    float* ws = (float*)d_ws;
    (void)in_sizes; (void)n_in; (void)out_size;

    float* bnsum = ws + OFF_BNS;
    float* cnss  = ws + OFF_CNSS;
    int*   flag  = (int*)(ws + OFF_FLAG);
    float* cvt   = ws + OFF_CVT;
    float* embF  = cvt + CVT_EMB;
    float* W1F   = cvt + CVT_W1;
    float* b1F   = cvt + CVT_B1;
    float* W2F   = cvt + CVT_W2;
    float* b2F   = cvt + CVT_B2;
    float* mlpWF = cvt + CVT_MLPW;
    float* mlpBF = cvt + CVT_MLPB;
    float* gamF  = cvt + CVT_GAMMA;
    float* betF  = cvt + CVT_BETA;
    u16*   Abf   = (u16*)(ws + OFF_ABF);
    float* rcnt  = ws + OFF_RC;
    uint*  P8    = (uint*)(ws + OFF_POOL);
    float* part  = ws + OFF_PART;
    u16*   H1hi  = (u16*)(ws + OFF_H1);
    u16*   H1lo  = H1hi + 64ull * NPAD;
    u16*   H2hi  = (u16*)(ws + OFF_H2);
    u16*   H2lo  = H2hi + 3ull * 64 * NPAD;
    float* out2  = ws + OFF_OUT2;
    float* cu    = ws + OFF_CU;
    float* ci    = ws + OFF_CI;
    float* hpre  = ws + OFF_H;

    // choose S (edge-slice count / partial copies) by workspace headroom
    size_t p8per = 3ull * NN * P8W;        // floats (==u32) per partial copy
    int S = 4;
    if      (ws_size >= (OFF_POOL + 16ull * p8per) * 4) S = 16;
    else if (ws_size >= (OFF_POOL +  8ull * p8per) * 4) S = 8;

    hipMemsetAsync(ws, 0, MEMSET_FLOATS * sizeof(float), stream);   // bnsum + cnss
    k_cvt_all<<<CVT_TOTAL / 256, 256, 0, stream>>>(
        presc, emb, W1, b1, W2, b2, mlpW, mlpB, gamma, beta, cvt, cnss, flag);

    k_histp<<<3 * RB * S, 512, 0, stream>>>(tg, s1, s2, P8, S);
    k_abfrc<<<3 * NN, 256, 0, stream>>>(P8, S, Abf, rcnt);

    // layer 1
    k_xf<<<MT, 256, 0, stream>>>(embF, 0, nullptr, nullptr, 0, W1F, b1F, H1hi, H1lo, 0);
    k_aggp<<<3 * MT * KT, 256, 0, stream>>>(Abf, H1hi, H1lo, 0, part);
    // layer 2
    k_xf<<<3 * MT, 256, 0, stream>>>(nullptr, 0, part, rcnt, 1, W2F, b2F, H2hi, H2lo, 64ull * NPAD);
    k_aggp<<<3 * MT * KT, 256, 0, stream>>>(Abf, H2hi, H2lo, 64ull * NPAD, part);
    k_comb<<<3 * CPG, 256, 0, stream>>>(part, rcnt, out2, cnss);

    // view fusion
    k_cuci<<<448 + NUSER, 64, 0, stream>>>(embF, out2, cnss, cu, ci);

    // pooling + MLP(+BN partials) + final GEMM
    k_esynd<<<BB / 16, 256, 0, stream>>>(presc, cu, mlpWF, mlpBF, flag, hpre, bnsum);
    k_final<<<(BB / 64) * FNT, 256, 0, stream>>>(hpre, bnsum, gamF, betF, ci, d_out, flag);
}